// Round 3
// baseline (48.935 us; speedup 1.0000x reference)
//
#include <hip/hip_runtime.h>
#include <hip/hip_bf16.h>

#define BB 2
#define NN 512
#define FIN 128
#define HH 4
#define DD 64
// lrelu(z) = 0.6*z + 0.4*|z|  (slope 0.2)

// ws layout (floats):
//  h_ws   [8][512][64]      262144  @ 0
//  zi_ws  [8][512][64]      262144  @ 262144   (includes W_cat_bias)
//  zj_ws  [8][512][64]      262144  @ 524288
//  adi_ws [8][512]          4096    @ 786432   (0.6 * sum_e a*zi)
//  adj_ws [8][512]          4096    @ 790528
//  pacc   [4][8][512][64]   1048576 @ 794624
//  pm     [4][8][512]       16384   @ 1843200
//  ps     [4][8][512]       16384   @ 1859584
// total 1875968 floats = 7.5 MB

// ---------------------------------------------------------------------------
// proj: h = x@Wp + bp ; zi = h@W1^T + Wcb ; zj = h@W2^T ; adi/adj dots
// grid = B*H*(N/8) = 512 blocks x 256 thr
// ---------------------------------------------------------------------------
__global__ __launch_bounds__(256) void proj_kernel(
    const float* __restrict__ x, const float* __restrict__ Wp,
    const float* __restrict__ bp, const float* __restrict__ Wc,
    const float* __restrict__ Wcb, const float* __restrict__ a,
    float* __restrict__ h_ws, float* __restrict__ zi_ws, float* __restrict__ zj_ws,
    float* __restrict__ adi_ws, float* __restrict__ adj_ws)
{
    int blk = blockIdx.x;
    int bh = blk >> 6;
    int n0 = (blk & 63) << 3;
    int b = bh >> 2, hh = bh & 3;

    __shared__ float xs[8 * FIN];          // 4 KB
    __shared__ float hs[8][DD];            // 2 KB
    __shared__ float Wcs[DD][2 * DD + 1];  // 64x129 = 33 KB

    int t = threadIdx.x;

    ((float4*)xs)[t] = ((const float4*)(x + ((size_t)b * NN + n0) * FIN))[t];
    {
        const float4* wg = (const float4*)(Wc + (size_t)hh * DD * 2 * DD);
        #pragma unroll
        for (int k = 0; k < 8; ++k) {
            int idx = t + 256 * k;               // 2048 float4 = 64x128
            int r = idx >> 5, c4 = (idx & 31) * 4;
            float4 v = wg[idx];
            Wcs[r][c4] = v.x; Wcs[r][c4 + 1] = v.y;
            Wcs[r][c4 + 2] = v.z; Wcs[r][c4 + 3] = v.w;
        }
    }
    __syncthreads();

    int d = t & 63, w = t >> 6;            // rows w, w+4
    const float* Wph = Wp + (size_t)hh * FIN * DD;
    float bpv = bp[hh * DD + d];
    float acc0 = bpv, acc1 = bpv;
    #pragma unroll 8
    for (int i = 0; i < FIN; ++i) {
        float wv = Wph[i * DD + d];        // coalesced, L1-hot
        acc0 = fmaf(xs[w * FIN + i], wv, acc0);
        acc1 = fmaf(xs[(w + 4) * FIN + i], wv, acc1);
    }
    hs[w][d] = acc0; hs[w + 4][d] = acc1;
    float* hg = h_ws + ((size_t)bh * NN + n0) * DD;
    hg[w * DD + d] = acc0; hg[(w + 4) * DD + d] = acc1;
    __syncthreads();

    int e = d;
    float zb = Wcb[hh * DD + e];
    float zi0 = zb, zi1 = zb, zj0 = 0.f, zj1 = 0.f;
    #pragma unroll 8
    for (int d2 = 0; d2 < DD; ++d2) {
        float w1 = Wcs[e][d2];
        float w2 = Wcs[e][DD + d2];
        float h0 = hs[w][d2], h1 = hs[w + 4][d2];   // broadcast
        zi0 = fmaf(h0, w1, zi0); zi1 = fmaf(h1, w1, zi1);
        zj0 = fmaf(h0, w2, zj0); zj1 = fmaf(h1, w2, zj1);
    }
    float* zib = zi_ws + ((size_t)bh * NN + n0) * DD;
    float* zjb = zj_ws + ((size_t)bh * NN + n0) * DD;
    zib[w * DD + e] = zi0; zib[(w + 4) * DD + e] = zi1;
    zjb[w * DD + e] = zj0; zjb[(w + 4) * DD + e] = zj1;

    // adi = 0.6*sum_e a*zi ; adj = 0.6*sum_e a*zj  (reduce across 64 lanes)
    float av = a[hh * DD + e];
    float p0 = av * zi0, p1 = av * zi1, q0 = av * zj0, q1 = av * zj1;
    #pragma unroll
    for (int off = 32; off; off >>= 1) {
        p0 += __shfl_xor(p0, off); p1 += __shfl_xor(p1, off);
        q0 += __shfl_xor(q0, off); q1 += __shfl_xor(q1, off);
    }
    if (e == 0) {
        adi_ws[bh * NN + n0 + w]     = 0.6f * p0;
        adi_ws[bh * NN + n0 + w + 4] = 0.6f * p1;
        adj_ws[bh * NN + n0 + w]     = 0.6f * q0;
        adj_ws[bh * NN + n0 + w + 4] = 0.6f * q1;
    }
}

// ---------------------------------------------------------------------------
// attn partial: Ti=16 rows, 128 j (js-split of 4). grid = 8*32*4 = 1024 blocks.
// Waves own 4 i-rows exclusively (pass A + PV). zi/a via scalar loads (SMEM).
// ---------------------------------------------------------------------------
__global__ __launch_bounds__(256) void attn_kernel(
    const float* __restrict__ h_ws, const float* __restrict__ zi_ws,
    const float* __restrict__ zj_ws, const float* __restrict__ a,
    const float* __restrict__ adi_ws, const float* __restrict__ adj_ws,
    float* __restrict__ pacc, float* __restrict__ pm, float* __restrict__ ps)
{
    int blk = blockIdx.x;
    int js = blk & 3;
    int it = (blk >> 2) & 31;
    int bh = blk >> 7;
    int i0 = it << 4;
    int hh = bh & 3;

    __shared__ float tile[64][68];     // 17.4 KB, b128 reads 8-per-bank balanced
    __shared__ float esT[128][20];     // 10 KB, row stride 80 B (16B-aligned)
    __shared__ float pms[16], pss[16];

    int t = threadIdx.x;
    int jl = t & 63;
    int w  = __builtin_amdgcn_readfirstlane(t >> 6);   // wave-uniform
    int r0 = i0 + 4 * w;

    // wave-uniform pointers -> scalar loads on the SMEM pipe
    const float4* zi0 = (const float4*)(zi_ws + ((size_t)bh * NN + r0 + 0) * DD);
    const float4* zi1 = (const float4*)(zi_ws + ((size_t)bh * NN + r0 + 1) * DD);
    const float4* zi2 = (const float4*)(zi_ws + ((size_t)bh * NN + r0 + 2) * DD);
    const float4* zi3 = (const float4*)(zi_ws + ((size_t)bh * NN + r0 + 3) * DD);
    const float4* a4  = (const float4*)(a + hh * DD);
    float adi0 = adi_ws[bh * NN + r0 + 0];
    float adi1 = adi_ws[bh * NN + r0 + 1];
    float adi2 = adi_ws[bh * NN + r0 + 2];
    float adi3 = adi_ws[bh * NN + r0 + 3];

    const float* zjb  = zj_ws + ((size_t)bh * NN + js * 128) * DD;
    const float* hb   = h_ws  + ((size_t)bh * NN + js * 128) * DD;
    const float* adjb = adj_ws + bh * NN + js * 128;

    // ---- Pass A: scores ----
    for (int jt = 0; jt < 2; ++jt) {
        __syncthreads();
        const float4* src = (const float4*)(zjb + (size_t)jt * 64 * DD);
        #pragma unroll
        for (int k = 0; k < 4; ++k) {
            int idx = t + 256 * k, r = idx >> 4, c4 = (idx & 15) * 4;
            float4 v = src[idx];
            tile[r][c4] = v.x; tile[r][c4 + 1] = v.y;
            tile[r][c4 + 2] = v.z; tile[r][c4 + 3] = v.w;
        }
        float adjv = adjb[jt * 64 + jl];
        __syncthreads();

        float acc0 = 0.f, acc1 = 0.f, acc2 = 0.f, acc3 = 0.f;
        const float4* trow = (const float4*)tile[jl];    // 272B rows, aligned
        #pragma unroll
        for (int e4 = 0; e4 < 16; ++e4) {
            float4 tv = trow[e4];                        // ds_read_b128
            float4 av = a4[e4];                          // s_load
            float4 z0 = zi0[e4], z1 = zi1[e4];           // s_load
            float4 z2 = zi2[e4], z3 = zi3[e4];
            acc0 = fmaf(av.x, __builtin_fabsf(z0.x + tv.x), acc0);
            acc0 = fmaf(av.y, __builtin_fabsf(z0.y + tv.y), acc0);
            acc0 = fmaf(av.z, __builtin_fabsf(z0.z + tv.z), acc0);
            acc0 = fmaf(av.w, __builtin_fabsf(z0.w + tv.w), acc0);
            acc1 = fmaf(av.x, __builtin_fabsf(z1.x + tv.x), acc1);
            acc1 = fmaf(av.y, __builtin_fabsf(z1.y + tv.y), acc1);
            acc1 = fmaf(av.z, __builtin_fabsf(z1.z + tv.z), acc1);
            acc1 = fmaf(av.w, __builtin_fabsf(z1.w + tv.w), acc1);
            acc2 = fmaf(av.x, __builtin_fabsf(z2.x + tv.x), acc2);
            acc2 = fmaf(av.y, __builtin_fabsf(z2.y + tv.y), acc2);
            acc2 = fmaf(av.z, __builtin_fabsf(z2.z + tv.z), acc2);
            acc2 = fmaf(av.w, __builtin_fabsf(z2.w + tv.w), acc2);
            acc3 = fmaf(av.x, __builtin_fabsf(z3.x + tv.x), acc3);
            acc3 = fmaf(av.y, __builtin_fabsf(z3.y + tv.y), acc3);
            acc3 = fmaf(av.z, __builtin_fabsf(z3.z + tv.z), acc3);
            acc3 = fmaf(av.w, __builtin_fabsf(z3.w + tv.w), acc3);
        }
        float4 es4;
        es4.x = adi0 + adjv + 0.4f * acc0;
        es4.y = adi1 + adjv + 0.4f * acc1;
        es4.z = adi2 + adjv + 0.4f * acc2;
        es4.w = adi3 + adjv + 0.4f * acc3;
        *(float4*)&esT[jt * 64 + jl][4 * w] = es4;       // one b128 write
    }
    __syncthreads();

    // ---- partial softmax: 16 rows x 16 lanes, 128 cols ----
    {
        int r = t >> 4, l = t & 15;
        float m = -1e30f;
        #pragma unroll
        for (int k = 0; k < 8; ++k) m = fmaxf(m, esT[l + 16 * k][r]);
        #pragma unroll
        for (int off = 8; off; off >>= 1) m = fmaxf(m, __shfl_xor(m, off));
        float s = 0.f;
        #pragma unroll
        for (int k = 0; k < 8; ++k) {
            float p = __expf(esT[l + 16 * k][r] - m);
            esT[l + 16 * k][r] = p;
            s += p;
        }
        #pragma unroll
        for (int off = 8; off; off >>= 1) s += __shfl_xor(s, off);
        if (l == 0) { pms[r] = m; pss[r] = s; }
    }

    // ---- Pass C: PV (unnormalized). wave w does rows r0..r0+3, all j ----
    float acc0 = 0.f, acc1 = 0.f, acc2 = 0.f, acc3 = 0.f;
    for (int jt = 0; jt < 2; ++jt) {
        __syncthreads();
        const float4* src = (const float4*)(hb + (size_t)jt * 64 * DD);
        #pragma unroll
        for (int k = 0; k < 4; ++k) {
            int idx = t + 256 * k, r = idx >> 4, c4 = (idx & 15) * 4;
            float4 v = src[idx];
            tile[r][c4] = v.x; tile[r][c4 + 1] = v.y;
            tile[r][c4 + 2] = v.z; tile[r][c4 + 3] = v.w;
        }
        __syncthreads();
        #pragma unroll 16
        for (int j = 0; j < 64; ++j) {
            float4 p = *(const float4*)&esT[jt * 64 + j][4 * w];  // broadcast
            float hv = tile[j][jl];                               // 2-way, free
            acc0 = fmaf(p.x, hv, acc0);
            acc1 = fmaf(p.y, hv, acc1);
            acc2 = fmaf(p.z, hv, acc2);
            acc3 = fmaf(p.w, hv, acc3);
        }
    }

    size_t rowbase = ((size_t)(js * 8 + bh) * NN + r0);
    pacc[(rowbase + 0) * DD + jl] = acc0;
    pacc[(rowbase + 1) * DD + jl] = acc1;
    pacc[(rowbase + 2) * DD + jl] = acc2;
    pacc[(rowbase + 3) * DD + jl] = acc3;
    if (t < 16) {
        pm[(js * 8 + bh) * NN + i0 + t] = pms[t];
        ps[(js * 8 + bh) * NN + i0 + t] = pss[t];
    }
}

// ---------------------------------------------------------------------------
// combine the 4 j-splits + bias. grid = 262144/256 = 1024 blocks.
// ---------------------------------------------------------------------------
__global__ __launch_bounds__(256) void combine_kernel(
    const float* __restrict__ pacc, const float* __restrict__ pm,
    const float* __restrict__ ps, const float* __restrict__ bias_param,
    float* __restrict__ out)
{
    int tid = blockIdx.x * 256 + threadIdx.x;
    int d = tid & 63;
    int row = tid >> 6;                 // bh*512 + n
    int bh = row >> 9, n = row & 511;
    int b = bh >> 2, hh = bh & 3;
    float m0 = pm[row],         m1 = pm[4096 + row];
    float m2 = pm[8192 + row],  m3 = pm[12288 + row];
    float M = fmaxf(fmaxf(m0, m1), fmaxf(m2, m3));
    float w0 = __expf(m0 - M), w1 = __expf(m1 - M);
    float w2 = __expf(m2 - M), w3 = __expf(m3 - M);
    float denom = ps[row] * w0 + ps[4096 + row] * w1
                + ps[8192 + row] * w2 + ps[12288 + row] * w3;
    float acc = pacc[(size_t)row * 64 + d] * w0
              + pacc[262144 + (size_t)row * 64 + d] * w1
              + pacc[524288 + (size_t)row * 64 + d] * w2
              + pacc[786432 + (size_t)row * 64 + d] * w3;
    out[((size_t)b * NN + n) * (HH * DD) + hh * DD + d] =
        acc / denom + bias_param[hh * DD + d];
}

extern "C" void kernel_launch(void* const* d_in, const int* in_sizes, int n_in,
                              void* d_out, int out_size, void* d_ws, size_t ws_size,
                              hipStream_t stream) {
    const float* x    = (const float*)d_in[0];
    const float* Wp   = (const float*)d_in[1];
    const float* bp   = (const float*)d_in[2];
    const float* Wc   = (const float*)d_in[3];
    const float* Wcb  = (const float*)d_in[4];
    const float* a    = (const float*)d_in[5];
    const float* bpar = (const float*)d_in[6];
    float* out = (float*)d_out;

    float* ws     = (float*)d_ws;
    float* h_ws   = ws;
    float* zi_ws  = ws + 262144;
    float* zj_ws  = ws + 524288;
    float* adi_ws = ws + 786432;
    float* adj_ws = ws + 790528;
    float* pacc   = ws + 794624;
    float* pm     = ws + 1843200;
    float* ps     = ws + 1859584;

    proj_kernel<<<dim3(512), dim3(256), 0, stream>>>(
        x, Wp, bp, Wc, Wcb, a, h_ws, zi_ws, zj_ws, adi_ws, adj_ws);
    attn_kernel<<<dim3(1024), dim3(256), 0, stream>>>(
        h_ws, zi_ws, zj_ws, a, adi_ws, adj_ws, pacc, pm, ps);
    combine_kernel<<<dim3(1024), dim3(256), 0, stream>>>(
        pacc, pm, ps, bpar, out);
}